// Round 6
// baseline (192.337 us; speedup 1.0000x reference)
//
#include <hip/hip_runtime.h>
#include <hip/hip_bf16.h>
#include <stdint.h>

#define NP 30000
#define BBINS 80
#define INCH 16
#define OUTCH 32
#define KDIM 1280       // BBINS*INCH
#define NDIM 512        // OUTCH*TBINS
#define KSTEPS 40       // KDIM/32  (BK=32 = 2 bins)
#define MTILES 469      // ceil(NP/64)

typedef __bf16 bf16x8 __attribute__((ext_vector_type(8)));
typedef float f32x4 __attribute__((ext_vector_type(4)));

__device__ __forceinline__ void async_ld16(const void* g, void* l) {
    __builtin_amdgcn_global_load_lds(
        (const __attribute__((address_space(1))) unsigned int*)g,
        (__attribute__((address_space(3))) unsigned int*)l,
        16, 0, 0);
}

// ---------------------------------------------------------------------------
// Prep: PW[kc][n][qs][e] bf16 with chunk-XOR swizzle qs ^ ((n>>1)&3), where
// lw[k][n] = W[(b+5t)%80][c][o], k=b*16+c, n=o*16+t. (unchanged, proven)
// ---------------------------------------------------------------------------
__global__ void prep_weights(const float* __restrict__ w, __bf16* __restrict__ pw) {
    int gid = blockIdx.x * 256 + threadIdx.x;           // 655360 total
    int e  = gid & 7;
    int qs = (gid >> 3) & 3;
    int n  = (gid >> 5) & 511;
    int kc = gid >> 14;                                  // 0..39
    int kp = kc * 32 + ((qs ^ ((n >> 1) & 3)) << 3) + e; // 0..1279
    int b = kp >> 4, c = kp & 15;
    int o = n >> 4,  t = n & 15;
    int bid = (b + 5 * t) % BBINS;
    pw[gid] = (__bf16)w[(bid * INCH + c) * OUTCH + o];
}

// ---------------------------------------------------------------------------
// FUSED gather + GEMM + max-over-t.
// R5 diagnosis: gather(57.5us) + gemm(~56us) are two latency-bound kernels
// whose ONLY coupling is the 76.8MB h tensor: 150MB of the pipeline's
// ~157MB HBM traffic is that round-trip. Irreducible traffic is ~63MB
// (metadata 57.6 + x 1.9 L2-resident + out 3.8); MFMA floor ~16us.
//
// Block: 64 patches x full N=512, 4 waves (wave n-col grid 1x4, wave tile
// 64x128 = proven 4x8 acc). Per k-step (BK=32 = bins {2kc,2kc+1}):
//  * B: 32KB staged via global_load_lds from pre-swizzled pw (verbatim R0-R5).
//  * A: GATHERED IN-KERNEL. Thread tid = unit (patch_l=tid>>2, bin_l, half):
//    3 meta + 6 float4 x-loads (x L2-resident) -> 8ch FMA -> one
//    ds_write_b128 into Alds at slot (chunk ^ ((patch_l>>1)&3)) -- the SAME
//    chunk-XOR scheme the a_off read side uses (slot q^((row>>1)&3)), now
//    applied at write time since we own the ds_write. Write pattern per
//    wave = 64 distinct 16B slots covering 1KB linearly-permuted ->
//    conflict-free.
//  * Metadata for kstep kc+1 is prefetched into regs during kc (its HBM
//    latency hides under the k-step), so the in-step chain is only
//    x-load(L2) -> FMA -> ds_write.
// Epilogue: identical shfl-max; o = wave*8+j.
// ---------------------------------------------------------------------------
__global__ __launch_bounds__(256, 2) void fused_gemm_max(
    const float* __restrict__ x,
    const int*   __restrict__ cidx,
    const float* __restrict__ cval,
    const __bf16* __restrict__ pw,
    float* __restrict__ out) {

    __shared__ __align__(16) __bf16 Alds[64 * 32];       // 4 KB
    __shared__ __align__(16) __bf16 Blds[512 * 32];      // 32 KB

    const int mbase = blockIdx.x * 64;
    const int tid  = threadIdx.x;
    const int lane = tid & 63;
    const int wave = tid >> 6;           // n-col group 0..3

    // ---- gather unit mapping ----
    const int patch_l = tid >> 2;        // 0..63
    const int chunk   = tid & 3;         // k-chunk within 64B row
    const int bin_l   = chunk >> 1;      // 0..1
    const int half    = chunk & 1;       // 8-ch half
    int p = mbase + patch_l;
    if (p > NP - 1) p = NP - 1;          // clamp tail (out-write guarded)
    const int row0 = p * BBINS + bin_l;  // conn row; +2 per kstep
    char* aW = (char*)Alds + patch_l * 64
             + ((chunk ^ ((patch_l >> 1) & 3)) << 4);   // swizzled write slot

    // ---- MFMA read offsets (proven swizzle) ----
    const int ml = lane & 15, q = lane >> 4;
    const int f = (ml >> 1) & 3;
    int a_off[4], b_off[8];
#pragma unroll
    for (int i = 0; i < 4; ++i)
        a_off[i] = (i * 16 + ml) * 64 + ((q ^ f) << 4);
#pragma unroll
    for (int j = 0; j < 8; ++j) {
        int nl = wave * 128 + j * 16 + ml;
        b_off[j] = nl * 64 + ((q ^ f) << 4);
    }

    f32x4 acc[4][8];
#pragma unroll
    for (int i = 0; i < 4; ++i)
#pragma unroll
        for (int j = 0; j < 8; ++j)
            acc[i][j] = (f32x4){0.f, 0.f, 0.f, 0.f};

    const char* pwB = (const char*)pw + tid * 16;
    char* bDst = (char*)Blds + tid * 16;

    // meta prefetch for kc=0
    int r3 = row0 * 3;
    int i0 = cidx[r3], i1 = cidx[r3 + 1], i2 = cidx[r3 + 2];
    float v0 = cval[r3], v1 = cval[r3 + 1], v2 = cval[r3 + 2];

    for (int kc = 0; kc < KSTEPS; ++kc) {
        // B: 32KB k-chunk, 8 x async 4KB (linear dest, swizzle baked in pw)
        const char* bs = pwB + kc * 32768;
#pragma unroll
        for (int i = 0; i < 8; ++i)
            async_ld16(bs + i * 4096, bDst + i * 4096);

        // A: gather this unit's 8 channels (meta already in regs)
        const float* xp0 = x + (size_t)(unsigned)i0 * 16 + half * 8;
        const float* xp1 = x + (size_t)(unsigned)i1 * 16 + half * 8;
        const float* xp2 = x + (size_t)(unsigned)i2 * 16 + half * 8;
        const float4 a0 = *(const float4*)xp0, a1 = *(const float4*)(xp0 + 4);
        const float4 b0 = *(const float4*)xp1, b1 = *(const float4*)(xp1 + 4);
        const float4 c0 = *(const float4*)xp2, c1 = *(const float4*)(xp2 + 4);
        bf16x8 hv;
        hv[0] = (__bf16)(v0 * a0.x + v1 * b0.x + v2 * c0.x);
        hv[1] = (__bf16)(v0 * a0.y + v1 * b0.y + v2 * c0.y);
        hv[2] = (__bf16)(v0 * a0.z + v1 * b0.z + v2 * c0.z);
        hv[3] = (__bf16)(v0 * a0.w + v1 * b0.w + v2 * c0.w);
        hv[4] = (__bf16)(v0 * a1.x + v1 * b1.x + v2 * c1.x);
        hv[5] = (__bf16)(v0 * a1.y + v1 * b1.y + v2 * c1.y);
        hv[6] = (__bf16)(v0 * a1.z + v1 * b1.z + v2 * c1.z);
        hv[7] = (__bf16)(v0 * a1.w + v1 * b1.w + v2 * c1.w);
        *(bf16x8*)aW = hv;                               // ds_write_b128

        // prefetch meta for next kstep (latency hides under this step)
        if (kc + 1 < KSTEPS) {
            r3 = (row0 + (kc + 1) * 2) * 3;
            i0 = cidx[r3]; i1 = cidx[r3 + 1]; i2 = cidx[r3 + 2];
            v0 = cval[r3]; v1 = cval[r3 + 1]; v2 = cval[r3 + 2];
        }
        __syncthreads();                                 // drains vm+lgkm

        bf16x8 af[4], bfr[8];
#pragma unroll
        for (int i = 0; i < 4; ++i)
            af[i] = *(const bf16x8*)((const char*)Alds + a_off[i]);
#pragma unroll
        for (int j = 0; j < 8; ++j)
            bfr[j] = *(const bf16x8*)((const char*)Blds + b_off[j]);
#pragma unroll
        for (int i = 0; i < 4; ++i)
#pragma unroll
            for (int j = 0; j < 8; ++j)
                acc[i][j] = __builtin_amdgcn_mfma_f32_16x16x32_bf16(
                    af[i], bfr[j], acc[i][j], 0, 0, 0);
        __syncthreads();
    }

    const int rgrp = lane >> 4;
    const int tl   = lane & 15;
#pragma unroll
    for (int i = 0; i < 4; ++i) {
#pragma unroll
        for (int j = 0; j < 8; ++j) {
            float v0r = acc[i][j][0], v1r = acc[i][j][1];
            float v2r = acc[i][j][2], v3r = acc[i][j][3];
#pragma unroll
            for (int off = 1; off < 16; off <<= 1) {
                v0r = fmaxf(v0r, __shfl_xor(v0r, off));
                v1r = fmaxf(v1r, __shfl_xor(v1r, off));
                v2r = fmaxf(v2r, __shfl_xor(v2r, off));
                v3r = fmaxf(v3r, __shfl_xor(v3r, off));
            }
            if (tl == 0) {
                const int o  = wave * 8 + j;
                const int pr = mbase + i * 16 + rgrp * 4;
                if (pr + 0 < NP) out[(pr + 0) * 32 + o] = v0r;
                if (pr + 1 < NP) out[(pr + 1) * 32 + o] = v1r;
                if (pr + 2 < NP) out[(pr + 2) * 32 + o] = v2r;
                if (pr + 3 < NP) out[(pr + 3) * 32 + o] = v3r;
            }
        }
    }
}

extern "C" void kernel_launch(void* const* d_in, const int* in_sizes, int n_in,
                              void* d_out, int out_size, void* d_ws, size_t ws_size,
                              hipStream_t stream) {
    const float* x    = (const float*)d_in[0];
    const int*   cidx = (const int*)d_in[1];
    const float* cval = (const float*)d_in[2];
    const float* w    = (const float*)d_in[3];
    float* out = (float*)d_out;

    __bf16* pw = (__bf16*)d_ws;                               // 1.31 MB

    hipLaunchKernelGGL(prep_weights, dim3(2560), dim3(256), 0, stream, w, pw);
    hipLaunchKernelGGL(fused_gemm_max, dim3(MTILES), dim3(256), 0, stream,
                       x, cidx, cval, (const __bf16*)pw, out);
}